// Round 5
// baseline (1015.067 us; speedup 1.0000x reference)
//
#include <hip/hip_runtime.h>

// Problem constants
#define NB 96
#define NQ 96
#define NV 197
#define NT 77
#define DK 768
#define DE 512

typedef __attribute__((ext_vector_type(8))) short s16x8;
typedef __attribute__((ext_vector_type(4))) float f32x4;
typedef long long i64;

__device__ __forceinline__ unsigned short f2bf(float f) {
  union { float f; unsigned int u; } v; v.f = f;
  unsigned int u = v.u;
  unsigned int r = u + 0x7fffu + ((u >> 16) & 1u);
  return (unsigned short)(r >> 16);
}

__device__ __forceinline__ unsigned int pack2bf(float a, float b) {
  return (unsigned int)f2bf(a) | ((unsigned int)f2bf(b) << 16);
}

// f32 -> OCP e4m3fn, round-to-nearest-even.  Inputs here are l2-normalized
// (|x| <= 1) so saturation never triggers; kept for safety.
__device__ __forceinline__ unsigned char f2fp8(float x) {
  union { float f; unsigned u; } v; v.f = x;
  unsigned s = (v.u >> 24) & 0x80;
  v.u &= 0x7FFFFFFFu;
  if (v.f < 0.015625f) {                       // |x| < 2^-6 -> subnormal
    int q = __float2int_rn(v.f * 512.0f);      // RNE; q in 0..8
    return (unsigned char)(s | (unsigned)q);
  }
  if (v.f >= 464.0f) return (unsigned char)(s | 0x7E);  // clamp to 448
  int e8 = (int)((v.u >> 23) & 0xFF) - 120;    // e4m3 biased exponent (bias 7)
  unsigned m = v.u & 0x7FFFFFu;
  unsigned t = ((unsigned)e8 << 3) | (m >> 20);
  unsigned r = m & 0xFFFFFu;
  t += (r > 0x80000u) || ((r == 0x80000u) && (t & 1u));
  if (t > 0x7Eu) t = 0x7Eu;
  return (unsigned char)(s | t);
}

// global -> LDS direct, 16B/lane.  LDS dest = uniform base + lane*16.
#define GL16(gp, lp, off)                                                \
  __builtin_amdgcn_global_load_lds(                                      \
      (const __attribute__((address_space(1))) void*)(gp),               \
      (__attribute__((address_space(3))) void*)(lp), 16, (off), 0)

#define VM_DRAIN() asm volatile("s_waitcnt vmcnt(0) lgkmcnt(0)" ::: "memory")

// ---------------------------------------------------------------------------
// K_prep: fused  cvt(Wv) | cvt(Wt) | cls_v | cls_t   via blockIdx ranges.
// ---------------------------------------------------------------------------
__global__ __launch_bounds__(256) void prep_kernel(
    const float* __restrict__ Wv_tok, unsigned short* __restrict__ Wvb,
    const float* __restrict__ Wt_tok, unsigned short* __restrict__ Wtb,
    const float* __restrict__ visual_cls, const float* __restrict__ Wv_cls,
    const float* __restrict__ bv_cls, float* __restrict__ v_cls_o,
    const float* __restrict__ textual_cls, const float* __restrict__ Wt_cls,
    const float* __restrict__ bt_cls, float* __restrict__ t_cls_o) {
  __shared__ float xs[DK];
  const int blk = blockIdx.x;
  const int tid = threadIdx.x;

  if (blk < 768) {
    const float* src = (blk < 384) ? Wv_tok : Wt_tok;
    unsigned short* dst = (blk < 384) ? Wvb : Wtb;
    int i = ((blk < 384) ? blk : (blk - 384)) * 256 + tid;
    float4 x = ((const float4*)src)[i];
    ushort4 h;
    h.x = f2bf(x.x); h.y = f2bf(x.y); h.z = f2bf(x.z); h.w = f2bf(x.w);
    ((ushort4*)dst)[i] = h;
    return;
  }
  const int is_t = (blk >= 864);
  const int row = blk - (is_t ? 864 : 768);
  const float* X = is_t ? textual_cls : visual_cls;
  const float* W = is_t ? Wt_cls : Wv_cls;
  const float* bias = is_t ? bt_cls : bv_cls;
  float* out = is_t ? t_cls_o : v_cls_o;

  const float* xr = X + (long)row * DK;
  for (int i = tid; i < DK; i += 256) xs[i] = xr[i];
  __syncthreads();
  for (int c = tid; c < DE; c += 256) {
    const float* wr = W + (long)c * DK;
    float s = 0.f;
    #pragma unroll 4
    for (int k = 0; k < DK; k += 4) {
      float4 w4 = *(const float4*)(wr + k);
      s += xs[k] * w4.x + xs[k + 1] * w4.y + xs[k + 2] * w4.z + xs[k + 3] * w4.w;
    }
    out[(long)row * DE + c] = s + bias[c];
  }
}

// ---------------------------------------------------------------------------
// K_proj: fused token projection + bias + l2norm for BOTH modalities.
// Output Y is FP8 e4m3fn (norm computed in f32 first).
// ---------------------------------------------------------------------------
__global__ __launch_bounds__(256, 2) void proj_norm_kernel(
    const float* __restrict__ Xv, const unsigned short* __restrict__ Wvb,
    const float* __restrict__ bv, unsigned char* __restrict__ Yv,
    const float* __restrict__ Xt, const unsigned short* __restrict__ Wtb,
    const float* __restrict__ bt, unsigned char* __restrict__ Yt) {
  __shared__ __align__(16) unsigned short Ws[512 * 64];  // 65536 B
  __shared__ __align__(16) unsigned short Xs[64 * 64];   // 8192 B
  __shared__ float ssq_lds[4][64];

  const int blk = blockIdx.x;
  const int is_t = (blk >= 296);
  const float* X = is_t ? Xt : Xv;
  const unsigned short* Wb = is_t ? Wtb : Wvb;
  const float* bias = is_t ? bt : bv;
  unsigned char* Y = is_t ? Yt : Yv;
  const int M = is_t ? (NQ * NT) : (NB * NV);
  const long row0 = (long)(is_t ? (blk - 296) : blk) * 64;

  const int tid = threadIdx.x;
  const int wave = tid >> 6;
  const int lane = tid & 63;
  const int l15 = lane & 15;
  const int quad = lane >> 4;

  const int sub = lane >> 3;                 // 0..7
  const int swz = ((lane & 7) ^ sub) << 3;   // element offset
  const unsigned short* pw_base = Wb + (long)(wave * 8 + sub) * DK + swz;

  const int xrow_a = tid >> 3;               // 0..31
  const int xrow_b = xrow_a + 32;            // 32..63
  const int xs8 = tid & 7;
  long gra = row0 + xrow_a; if (gra > M - 1) gra = M - 1;
  long grb = row0 + xrow_b; if (grb > M - 1) grb = M - 1;
  const float* px_a = X + gra * DK + xs8 * 8;
  const float* px_b = X + grb * DK + xs8 * 8;
  const int xaddr_a = (xrow_a << 6) + ((xs8 ^ (xrow_a & 7)) << 3);
  const int xaddr_b = (xrow_b << 6) + ((xs8 ^ (xrow_b & 7)) << 3);

  f32x4 acc[4][8];
  #pragma unroll
  for (int m = 0; m < 4; ++m)
    #pragma unroll
    for (int n = 0; n < 8; ++n)
      acc[m][n] = (f32x4){0.f, 0.f, 0.f, 0.f};

  for (int kc = 0; kc < DK; kc += 64) {
    __syncthreads();
    {
      float4 x0 = *(const float4*)(px_a);
      float4 x1 = *(const float4*)(px_a + 4);
      uint4 h;
      h.x = pack2bf(x0.x, x0.y); h.y = pack2bf(x0.z, x0.w);
      h.z = pack2bf(x1.x, x1.y); h.w = pack2bf(x1.z, x1.w);
      *(uint4*)(&Xs[xaddr_a]) = h;
      x0 = *(const float4*)(px_b);
      x1 = *(const float4*)(px_b + 4);
      h.x = pack2bf(x0.x, x0.y); h.y = pack2bf(x0.z, x0.w);
      h.z = pack2bf(x1.x, x1.y); h.w = pack2bf(x1.z, x1.w);
      *(uint4*)(&Xs[xaddr_b]) = h;
      px_a += 64; px_b += 64;
    }
    {
      const unsigned short* pw = pw_base;
      #pragma unroll
      for (int j = 0; j < 16; ++j) {
        GL16(pw, &Ws[(j * 4 + wave) << 9], 0);
        pw += 32 * DK;
      }
      pw_base += 64;
    }
    VM_DRAIN();
    __syncthreads();
    #pragma unroll
    for (int ks = 0; ks < 2; ++ks) {
      s16x8 af[4];
      #pragma unroll
      for (int mi = 0; mi < 4; ++mi) {
        int arow = mi * 16 + l15;
        af[mi] = *(const s16x8*)&Xs[(arow << 6) + ((((ks << 2) + quad) ^ (arow & 7)) << 3)];
      }
      #pragma unroll
      for (int nt = 0; nt < 8; ++nt) {
        int wrow = wave * 128 + nt * 16 + l15;
        s16x8 bfr = *(const s16x8*)&Ws[(wrow << 6) + ((((ks << 2) + quad) ^ (wrow & 7)) << 3)];
        #pragma unroll
        for (int mi = 0; mi < 4; ++mi)
          acc[mi][nt] = __builtin_amdgcn_mfma_f32_16x16x32_bf16(af[mi], bfr, acc[mi][nt], 0, 0, 0);
      }
    }
  }

  #pragma unroll
  for (int nt = 0; nt < 8; ++nt) {
    float bc = bias[wave * 128 + nt * 16 + l15];
    #pragma unroll
    for (int mi = 0; mi < 4; ++mi) {
      acc[mi][nt].x += bc; acc[mi][nt].y += bc; acc[mi][nt].z += bc; acc[mi][nt].w += bc;
    }
  }

  #pragma unroll
  for (int mi = 0; mi < 4; ++mi)
    #pragma unroll
    for (int r = 0; r < 4; ++r) {
      float t = 0.f;
      #pragma unroll
      for (int nt = 0; nt < 8; ++nt) { float v = acc[mi][nt][r]; t += v * v; }
      t += __shfl_xor(t, 1);
      t += __shfl_xor(t, 2);
      t += __shfl_xor(t, 4);
      t += __shfl_xor(t, 8);
      if (l15 == 0) ssq_lds[wave][mi * 16 + quad * 4 + r] = t;
    }
  __syncthreads();

  #pragma unroll
  for (int mi = 0; mi < 4; ++mi) {
    #pragma unroll
    for (int r = 0; r < 4; ++r) {
      int rr = mi * 16 + quad * 4 + r;
      float tot = ssq_lds[0][rr] + ssq_lds[1][rr] + ssq_lds[2][rr] + ssq_lds[3][rr];
      float scale = (tot > 0.f) ? (1.f / fmaxf(sqrtf(tot), 1e-12f)) : 0.f;
      long grow = row0 + rr;
      if (grow < M) {
        #pragma unroll
        for (int nt = 0; nt < 8; ++nt) {
          int col = wave * 128 + nt * 16 + l15;
          Y[grow * DE + col] = f2fp8(acc[mi][nt][r] * scale);
        }
      }
    }
  }
}

// ---------------------------------------------------------------------------
// K3: fused similarity + masked max/sum reductions.  FP8 e4m3 inputs.
// r4 post-mortem: nothing saturated (MfmaUtil 29%, VALU 41%, HBM 1%) at
// OccupancyPercent 22% (2 blocks/CU) -> LATENCY-BOUND.  fp8 freed LDS, so:
// DOUBLE-buffer (47 KB total) -> 3 blocks/CU (launch_bounds 256,3).
// Depth-1 prefetch, one barrier/chunk:
//   iter c: wait vmcnt(0) [own chunk-c loads] -> barrier [publish c; buf
//   1-cur free since everyone computed c-1 before this barrier] ->
//   stage c+1 into buf 1-cur -> compute c.
// Stage gets a full compute phase of cover; 3rd block hides the rest.
// ---------------------------------------------------------------------------
__global__ __launch_bounds__(256, 3) void score_kernel(
    const unsigned char* __restrict__ Yv, const unsigned char* __restrict__ Yt,
    const int* __restrict__ tlen, float* __restrict__ t2v, float* __restrict__ v2t) {
  __shared__ __align__(16) unsigned char As[2][104 * 128];  // 2 x 13312 B
  __shared__ __align__(16) unsigned char Bs[2][80 * 128];   // 2 x 10240 B
  __shared__ float colbuf[4][160];
  __shared__ float rowsum_lds[4][2];

  const int tid = threadIdx.x;
  const int wave = tid >> 6;
  const int lane = tid & 63;
  const int l15 = lane & 15;
  const int quad = lane >> 4;

  // qi-outer / b-inner per-XCD swizzle (keeps the XCD's A working set
  // L2-resident; r3 measured FETCH 285->48 MB).
  const int idx = blockIdx.x;
  const int x = idx & 7;
  const int g = idx >> 3;              // 0..575
  const int qi = g / 12;               // 0..47
  const int bslot = g - qi * 12;       // 0..11
  const int b = bslot * 8 + x;
  const int q0 = qi * 2;

  const unsigned char* Ab = Yv + (long)b * (NV * DE);
  const unsigned char* Bb = Yt + (long)q0 * (NT * DE);

  // ---- zero-init LDS (safety net) ----
  {
    unsigned int* za = (unsigned int*)&As[0][0];
    for (int i = tid; i < 6656; i += 256) za[i] = 0;   // 2*13312 B
    unsigned int* zb = (unsigned int*)&Bs[0][0];
    for (int i = tid; i < 5120; i += 256) zb[i] = 0;   // 2*10240 B
  }
  __syncthreads();

  // ---- staging pointers (bytes) ----
  // segment s covers units s*8..s*8+7; lane: ul=lane>>3, slot=lane&7
  // row = unit*2 + (slot&1); k-quad (16 B) = (slot>>1) ^ (ul&3)
  const int ul = lane >> 3;
  const int slot = lane & 7;
  const int kq16 = (((slot >> 1) ^ (ul & 3)) << 4);  // byte offset in 64-B chunk

  auto a_ptr = [&](int s) -> const unsigned char* {
    int row = (s * 8 + ul) * 2 + (slot & 1);
    if (row > NV - 1) row = NV - 1;
    return Ab + row * DE + kq16;
  };
  auto b_ptr = [&](int s) -> const unsigned char* {
    int r = (s * 8 + ul) * 2 + (slot & 1);
    int half = (r >= 80) ? 1 : 0;
    int t = r - 80 * half;
    if (t > NT - 1) t = NT - 1;
    return Bb + (long)half * (NT * DE) + t * DE + kq16;
  };

  const unsigned char* sp0 = a_ptr(wave);        // A segs 0..3
  const unsigned char* sp1 = a_ptr(wave + 4);    // A segs 4..7
  const unsigned char* sp2 = a_ptr(wave + 8);    // A segs 8..11
  const int s3 = (wave == 1) ? 8 : (wave == 2) ? 9 : 12;
  const int b3_is_b = (wave == 1 || wave == 2);
  const unsigned char* sp3 = b3_is_b ? b_ptr(s3) : a_ptr(12);
  const unsigned char* sp4 = b_ptr(wave);        // B segs 0..3
  const unsigned char* sp5 = b_ptr(wave + 4);    // B segs 4..7
  unsigned char* b3d0 = b3_is_b ? &Bs[0][s3 << 10] : &As[0][12 << 10];
  unsigned char* b3d1 = b3_is_b ? &Bs[1][s3 << 10] : &As[1][12 << 10];

  // ---- k-invariant LDS fragment byte offsets ----
  const int qh = quad >> 1;
  const int q8 = (quad & 1) << 3;
  int aoff[4], boff[10];
  #pragma unroll
  for (int i = 0; i < 4; ++i) {
    int arow = (wave + i * 4) * 16 + l15;
    int u = arow >> 1;
    aoff[i] = (u << 7) + (((qh ^ (u & 3))) << 5) + ((arow & 1) << 4) + q8;
  }
  #pragma unroll
  for (int nt = 0; nt < 10; ++nt) {
    int brow = nt * 16 + l15;
    int u = brow >> 1;
    boff[nt] = (u << 7) + (((qh ^ (u & 3))) << 5) + ((brow & 1) << 4) + q8;
  }

  f32x4 acc[4][10];
  #pragma unroll
  for (int i = 0; i < 4; ++i)
    #pragma unroll
    for (int nt = 0; nt < 10; ++nt)
      acc[i][nt] = (f32x4){0.f, 0.f, 0.f, 0.f};

  auto do_compute = [&](int p) {
    #pragma unroll
    for (int ks = 0; ks < 2; ++ks) {
      const int kx = ks ? 64 : 0;        // flips kq bit 1 in the XOR'd field
      i64 bf[10];
      #pragma unroll
      for (int nt = 0; nt < 10; ++nt)
        bf[nt] = *(const i64*)&Bs[p][boff[nt] ^ kx];
      __builtin_amdgcn_s_setprio(1);
      #pragma unroll
      for (int i = 0; i < 4; ++i) {
        int mt = wave + (i << 2);
        if (mt < 13) {
          i64 af = *(const i64*)&As[p][aoff[i] ^ kx];
          #pragma unroll
          for (int nt = 0; nt < 10; ++nt)
            acc[i][nt] = __builtin_amdgcn_mfma_f32_16x16x32_fp8_fp8(af, bf[nt], acc[i][nt], 0, 0, 0);
        }
      }
      __builtin_amdgcn_s_setprio(0);
    }
  };

  // stage current K-chunk (64 B/row) into buffer p; advance ptrs 64 B
#define SCORE_STAGE(p, b3p)                                              \
  {                                                                      \
    GL16(sp0, &As[p][(wave) << 10], 0);                                  \
    GL16(sp1, &As[p][(wave + 4) << 10], 0);                              \
    GL16(sp2, &As[p][(wave + 8) << 10], 0);                              \
    GL16(sp3, (b3p), 0);                                                 \
    GL16(sp4, &Bs[p][(wave) << 10], 0);                                  \
    GL16(sp5, &Bs[p][(wave + 4) << 10], 0);                              \
    sp0 += 64; sp1 += 64; sp2 += 64; sp3 += 64; sp4 += 64; sp5 += 64;    \
  }

  // iter c: own-wait (chunk c landed) -> barrier (publish; other buf free)
  // -> stage chunk c+1 -> compute chunk c.
#define SCORE_ITER(cur, b3p, do_stage)                                   \
  {                                                                      \
    asm volatile("s_waitcnt vmcnt(0)" ::: "memory");                     \
    __syncthreads();                                                     \
    if (do_stage) SCORE_STAGE(1 - (cur), b3p);                           \
    do_compute(cur);                                                     \
  }

  SCORE_STAGE(0, b3d0)        // chunk 0 -> buf0
  SCORE_ITER(0, b3d1, 1)      // c0: stage c1 -> buf1
  SCORE_ITER(1, b3d0, 1)      // c1: stage c2 -> buf0
  SCORE_ITER(0, b3d1, 1)      // c2
  SCORE_ITER(1, b3d0, 1)      // c3
  SCORE_ITER(0, b3d1, 1)      // c4
  SCORE_ITER(1, b3d0, 1)      // c5
  SCORE_ITER(0, b3d1, 1)      // c6: stage c7 -> buf1
  SCORE_ITER(1, b3d0, 0)      // c7: no stage

#undef SCORE_ITER
#undef SCORE_STAGE

  const int len0 = tlen[q0];
  const int len1 = tlen[q0 + 1];

  // ---- column max over valid v rows (t2v path), both q halves ----
  #pragma unroll
  for (int nt = 0; nt < 10; ++nt) {
    float m = -1e30f;
    #pragma unroll
    for (int i = 0; i < 4; ++i) {
      int mt = wave + (i << 2);
      if (mt < 13) {
        int mbase = mt * 16 + quad * 4;
        #pragma unroll
        for (int r = 0; r < 4; ++r)
          if (mbase + r < NV) m = fmaxf(m, acc[i][nt][r]);
      }
    }
    m = fmaxf(m, __shfl_xor(m, 16));
    m = fmaxf(m, __shfl_xor(m, 32));
    if (lane < 16) colbuf[wave][nt * 16 + l15] = m;
  }

  // ---- row max over valid t cols (v2t path), per q half ----
  float psum[2] = {0.f, 0.f};
  #pragma unroll
  for (int h = 0; h < 2; ++h) {
    int len = h ? len1 : len0;
    #pragma unroll
    for (int i = 0; i < 4; ++i) {
      int mt = wave + (i << 2);
      if (mt < 13) {
        int mbase = mt * 16 + quad * 4;
        #pragma unroll
        for (int r = 0; r < 4; ++r) {
          float rm = -1e30f;
          #pragma unroll
          for (int nt = 0; nt < 5; ++nt) {
            int c = nt * 16 + l15;
            if (c < len) rm = fmaxf(rm, acc[i][h * 5 + nt][r]);
          }
          rm = fmaxf(rm, __shfl_xor(rm, 1));
          rm = fmaxf(rm, __shfl_xor(rm, 2));
          rm = fmaxf(rm, __shfl_xor(rm, 4));
          rm = fmaxf(rm, __shfl_xor(rm, 8));
          if (len < NT) rm = fmaxf(rm, 0.f);  // masked zeros participate in max
          if (l15 == 0 && (mbase + r) < NV) psum[h] += rm;
        }
      }
    }
    psum[h] += __shfl_xor(psum[h], 16);
    psum[h] += __shfl_xor(psum[h], 32);
  }
  if (lane == 0) { rowsum_lds[wave][0] = psum[0]; rowsum_lds[wave][1] = psum[1]; }
  __syncthreads();

  if (wave < 2) {
    int q = q0 + wave;
    int len = wave ? len1 : len0;
    int cbase = wave * 80;
    float ssum = 0.f;
    for (int c = lane; c < 80; c += 64) {
      if (c < len) {
        float m = fmaxf(fmaxf(colbuf[0][cbase + c], colbuf[1][cbase + c]),
                        fmaxf(colbuf[2][cbase + c], colbuf[3][cbase + c]));
        ssum += m;
      }
    }
    ssum += __shfl_xor(ssum, 1);
    ssum += __shfl_xor(ssum, 2);
    ssum += __shfl_xor(ssum, 4);
    ssum += __shfl_xor(ssum, 8);
    ssum += __shfl_xor(ssum, 16);
    ssum += __shfl_xor(ssum, 32);
    if (lane == 0) {
      float rs = rowsum_lds[0][wave] + rowsum_lds[1][wave] +
                 rowsum_lds[2][wave] + rowsum_lds[3][wave];
      t2v[b * NQ + q] = ssum / (float)len;
      v2t[b * NQ + q] = rs / (float)NV;
    }
  }
}

// ---------------------------------------------------------------------------
extern "C" void kernel_launch(void* const* d_in, const int* in_sizes, int n_in,
                              void* d_out, int out_size, void* d_ws, size_t ws_size,
                              hipStream_t stream) {
  (void)in_sizes; (void)n_in; (void)out_size; (void)ws_size;
  const float* visual_cls     = (const float*)d_in[0];
  const float* visual_tokens  = (const float*)d_in[1];
  const float* textual_cls    = (const float*)d_in[2];
  const float* textual_tokens = (const float*)d_in[3];
  const float* Wv_cls = (const float*)d_in[4];
  const float* bv_cls = (const float*)d_in[5];
  const float* Wt_cls = (const float*)d_in[6];
  const float* bt_cls = (const float*)d_in[7];
  const float* Wv_tok = (const float*)d_in[8];
  const float* bv_tok = (const float*)d_in[9];
  const float* Wt_tok = (const float*)d_in[10];
  const float* bt_tok = (const float*)d_in[11];
  const int* text_length = (const int*)d_in[12];

  float* out = (float*)d_out;
  float* v_cls_o = out;
  float* t_cls_o = out + 49152;
  float* t2v_o   = out + 98304;
  float* v2t_o   = out + 107520;

  char* ws = (char*)d_ws;
  unsigned short* Wvb = (unsigned short*)(ws);
  unsigned short* Wtb = (unsigned short*)(ws + 786432);
  unsigned char*  Yv  = (unsigned char*)(ws + 1572864);               // 96*197*512 B
  unsigned char*  Yt  = (unsigned char*)(ws + 1572864 + 9683968);     // 96*77*512 B

  prep_kernel<<<960, 256, 0, stream>>>(
      Wv_tok, Wvb, Wt_tok, Wtb,
      visual_cls, Wv_cls, bv_cls, v_cls_o,
      textual_cls, Wt_cls, bt_cls, t_cls_o);

  proj_norm_kernel<<<412, 256, 0, stream>>>(
      visual_tokens, Wvb, bv_tok, Yv,
      textual_tokens, Wtb, bt_tok, Yt);

  score_kernel<<<(NB * NQ) / 2, 256, 0, stream>>>(Yv, Yt, text_length, t2v_o, v2t_o);
}

// Round 6
// 416.749 us; speedup vs baseline: 2.4357x; 2.4357x over previous
//
#include <hip/hip_runtime.h>

// Problem constants
#define NB 96
#define NQ 96
#define NV 197
#define NT 77
#define DK 768
#define DE 512

typedef __attribute__((ext_vector_type(8))) short s16x8;
typedef __attribute__((ext_vector_type(4))) float f32x4;
typedef long long i64;

__device__ __forceinline__ unsigned short f2bf(float f) {
  union { float f; unsigned int u; } v; v.f = f;
  unsigned int u = v.u;
  unsigned int r = u + 0x7fffu + ((u >> 16) & 1u);
  return (unsigned short)(r >> 16);
}

__device__ __forceinline__ unsigned int pack2bf(float a, float b) {
  return (unsigned int)f2bf(a) | ((unsigned int)f2bf(b) << 16);
}

// f32 -> OCP e4m3fn, round-to-nearest-even.  Inputs here are l2-normalized
// (|x| <= 1) so saturation never triggers; kept for safety.
__device__ __forceinline__ unsigned char f2fp8(float x) {
  union { float f; unsigned u; } v; v.f = x;
  unsigned s = (v.u >> 24) & 0x80;
  v.u &= 0x7FFFFFFFu;
  if (v.f < 0.015625f) {                       // |x| < 2^-6 -> subnormal
    int q = __float2int_rn(v.f * 512.0f);      // RNE; q in 0..8
    return (unsigned char)(s | (unsigned)q);
  }
  if (v.f >= 464.0f) return (unsigned char)(s | 0x7E);  // clamp to 448
  int e8 = (int)((v.u >> 23) & 0xFF) - 120;    // e4m3 biased exponent (bias 7)
  unsigned m = v.u & 0x7FFFFFu;
  unsigned t = ((unsigned)e8 << 3) | (m >> 20);
  unsigned r = m & 0xFFFFFu;
  t += (r > 0x80000u) || ((r == 0x80000u) && (t & 1u));
  if (t > 0x7Eu) t = 0x7Eu;
  return (unsigned char)(s | t);
}

// global -> LDS direct, 16B/lane.  LDS dest = uniform base + lane*16.
#define GL16(gp, lp, off)                                                \
  __builtin_amdgcn_global_load_lds(                                      \
      (const __attribute__((address_space(1))) void*)(gp),               \
      (__attribute__((address_space(3))) void*)(lp), 16, (off), 0)

#define VM_DRAIN() asm volatile("s_waitcnt vmcnt(0) lgkmcnt(0)" ::: "memory")

// ---------------------------------------------------------------------------
// K_prep: fused  cvt(Wv) | cvt(Wt) | cls_v | cls_t   via blockIdx ranges.
// ---------------------------------------------------------------------------
__global__ __launch_bounds__(256) void prep_kernel(
    const float* __restrict__ Wv_tok, unsigned short* __restrict__ Wvb,
    const float* __restrict__ Wt_tok, unsigned short* __restrict__ Wtb,
    const float* __restrict__ visual_cls, const float* __restrict__ Wv_cls,
    const float* __restrict__ bv_cls, float* __restrict__ v_cls_o,
    const float* __restrict__ textual_cls, const float* __restrict__ Wt_cls,
    const float* __restrict__ bt_cls, float* __restrict__ t_cls_o) {
  __shared__ float xs[DK];
  const int blk = blockIdx.x;
  const int tid = threadIdx.x;

  if (blk < 768) {
    const float* src = (blk < 384) ? Wv_tok : Wt_tok;
    unsigned short* dst = (blk < 384) ? Wvb : Wtb;
    int i = ((blk < 384) ? blk : (blk - 384)) * 256 + tid;
    float4 x = ((const float4*)src)[i];
    ushort4 h;
    h.x = f2bf(x.x); h.y = f2bf(x.y); h.z = f2bf(x.z); h.w = f2bf(x.w);
    ((ushort4*)dst)[i] = h;
    return;
  }
  const int is_t = (blk >= 864);
  const int row = blk - (is_t ? 864 : 768);
  const float* X = is_t ? textual_cls : visual_cls;
  const float* W = is_t ? Wt_cls : Wv_cls;
  const float* bias = is_t ? bt_cls : bv_cls;
  float* out = is_t ? t_cls_o : v_cls_o;

  const float* xr = X + (long)row * DK;
  for (int i = tid; i < DK; i += 256) xs[i] = xr[i];
  __syncthreads();
  for (int c = tid; c < DE; c += 256) {
    const float* wr = W + (long)c * DK;
    float s = 0.f;
    #pragma unroll 4
    for (int k = 0; k < DK; k += 4) {
      float4 w4 = *(const float4*)(wr + k);
      s += xs[k] * w4.x + xs[k + 1] * w4.y + xs[k + 2] * w4.z + xs[k + 3] * w4.w;
    }
    out[(long)row * DE + c] = s + bias[c];
  }
}

// ---------------------------------------------------------------------------
// K_proj: fused token projection + bias + l2norm for BOTH modalities.
// Output Y is FP8 e4m3fn (norm computed in f32 first).
// ---------------------------------------------------------------------------
__global__ __launch_bounds__(256, 2) void proj_norm_kernel(
    const float* __restrict__ Xv, const unsigned short* __restrict__ Wvb,
    const float* __restrict__ bv, unsigned char* __restrict__ Yv,
    const float* __restrict__ Xt, const unsigned short* __restrict__ Wtb,
    const float* __restrict__ bt, unsigned char* __restrict__ Yt) {
  __shared__ __align__(16) unsigned short Ws[512 * 64];  // 65536 B
  __shared__ __align__(16) unsigned short Xs[64 * 64];   // 8192 B
  __shared__ float ssq_lds[4][64];

  const int blk = blockIdx.x;
  const int is_t = (blk >= 296);
  const float* X = is_t ? Xt : Xv;
  const unsigned short* Wb = is_t ? Wtb : Wvb;
  const float* bias = is_t ? bt : bv;
  unsigned char* Y = is_t ? Yt : Yv;
  const int M = is_t ? (NQ * NT) : (NB * NV);
  const long row0 = (long)(is_t ? (blk - 296) : blk) * 64;

  const int tid = threadIdx.x;
  const int wave = tid >> 6;
  const int lane = tid & 63;
  const int l15 = lane & 15;
  const int quad = lane >> 4;

  const int sub = lane >> 3;                 // 0..7
  const int swz = ((lane & 7) ^ sub) << 3;   // element offset
  const unsigned short* pw_base = Wb + (long)(wave * 8 + sub) * DK + swz;

  const int xrow_a = tid >> 3;               // 0..31
  const int xrow_b = xrow_a + 32;            // 32..63
  const int xs8 = tid & 7;
  long gra = row0 + xrow_a; if (gra > M - 1) gra = M - 1;
  long grb = row0 + xrow_b; if (grb > M - 1) grb = M - 1;
  const float* px_a = X + gra * DK + xs8 * 8;
  const float* px_b = X + grb * DK + xs8 * 8;
  const int xaddr_a = (xrow_a << 6) + ((xs8 ^ (xrow_a & 7)) << 3);
  const int xaddr_b = (xrow_b << 6) + ((xs8 ^ (xrow_b & 7)) << 3);

  f32x4 acc[4][8];
  #pragma unroll
  for (int m = 0; m < 4; ++m)
    #pragma unroll
    for (int n = 0; n < 8; ++n)
      acc[m][n] = (f32x4){0.f, 0.f, 0.f, 0.f};

  for (int kc = 0; kc < DK; kc += 64) {
    __syncthreads();
    {
      float4 x0 = *(const float4*)(px_a);
      float4 x1 = *(const float4*)(px_a + 4);
      uint4 h;
      h.x = pack2bf(x0.x, x0.y); h.y = pack2bf(x0.z, x0.w);
      h.z = pack2bf(x1.x, x1.y); h.w = pack2bf(x1.z, x1.w);
      *(uint4*)(&Xs[xaddr_a]) = h;
      x0 = *(const float4*)(px_b);
      x1 = *(const float4*)(px_b + 4);
      h.x = pack2bf(x0.x, x0.y); h.y = pack2bf(x0.z, x0.w);
      h.z = pack2bf(x1.x, x1.y); h.w = pack2bf(x1.z, x1.w);
      *(uint4*)(&Xs[xaddr_b]) = h;
      px_a += 64; px_b += 64;
    }
    {
      const unsigned short* pw = pw_base;
      #pragma unroll
      for (int j = 0; j < 16; ++j) {
        GL16(pw, &Ws[(j * 4 + wave) << 9], 0);
        pw += 32 * DK;
      }
      pw_base += 64;
    }
    VM_DRAIN();
    __syncthreads();
    #pragma unroll
    for (int ks = 0; ks < 2; ++ks) {
      s16x8 af[4];
      #pragma unroll
      for (int mi = 0; mi < 4; ++mi) {
        int arow = mi * 16 + l15;
        af[mi] = *(const s16x8*)&Xs[(arow << 6) + ((((ks << 2) + quad) ^ (arow & 7)) << 3)];
      }
      #pragma unroll
      for (int nt = 0; nt < 8; ++nt) {
        int wrow = wave * 128 + nt * 16 + l15;
        s16x8 bfr = *(const s16x8*)&Ws[(wrow << 6) + ((((ks << 2) + quad) ^ (wrow & 7)) << 3)];
        #pragma unroll
        for (int mi = 0; mi < 4; ++mi)
          acc[mi][nt] = __builtin_amdgcn_mfma_f32_16x16x32_bf16(af[mi], bfr, acc[mi][nt], 0, 0, 0);
      }
    }
  }

  #pragma unroll
  for (int nt = 0; nt < 8; ++nt) {
    float bc = bias[wave * 128 + nt * 16 + l15];
    #pragma unroll
    for (int mi = 0; mi < 4; ++mi) {
      acc[mi][nt].x += bc; acc[mi][nt].y += bc; acc[mi][nt].z += bc; acc[mi][nt].w += bc;
    }
  }

  #pragma unroll
  for (int mi = 0; mi < 4; ++mi)
    #pragma unroll
    for (int r = 0; r < 4; ++r) {
      float t = 0.f;
      #pragma unroll
      for (int nt = 0; nt < 8; ++nt) { float v = acc[mi][nt][r]; t += v * v; }
      t += __shfl_xor(t, 1);
      t += __shfl_xor(t, 2);
      t += __shfl_xor(t, 4);
      t += __shfl_xor(t, 8);
      if (l15 == 0) ssq_lds[wave][mi * 16 + quad * 4 + r] = t;
    }
  __syncthreads();

  #pragma unroll
  for (int mi = 0; mi < 4; ++mi) {
    #pragma unroll
    for (int r = 0; r < 4; ++r) {
      int rr = mi * 16 + quad * 4 + r;
      float tot = ssq_lds[0][rr] + ssq_lds[1][rr] + ssq_lds[2][rr] + ssq_lds[3][rr];
      float scale = (tot > 0.f) ? (1.f / fmaxf(sqrtf(tot), 1e-12f)) : 0.f;
      long grow = row0 + rr;
      if (grow < M) {
        #pragma unroll
        for (int nt = 0; nt < 8; ++nt) {
          int col = wave * 128 + nt * 16 + l15;
          Y[grow * DE + col] = f2fp8(acc[mi][nt][r] * scale);
        }
      }
    }
  }
}

// ---------------------------------------------------------------------------
// K3: fused similarity + masked max/sum reductions.  FP8 e4m3 inputs.
// r5 post-mortem: __launch_bounds__(256,3) capped VGPR at 84 and spilled
// the 160-reg accumulator to scratch (WRITE_SIZE 86 KB -> 2.06 GB) — 4x
// regression.  The occupancy goal is reached WITHOUT the cap: the
// double-buffer LDS footprint (50 KB) already allows 3 blocks/CU from
// the LDS limit alone.  So: launch_bounds(256,2) (compiler keeps its
// natural 116 VGPR, no spills), LDS-limited occupancy = 3 blocks/CU,
// 6 sequential rounds instead of 9.
// Depth-1 prefetch, one barrier/chunk (validated in r5):
//   iter c: wait vmcnt(0) -> barrier -> stage c+1 into other buf -> compute c.
// ---------------------------------------------------------------------------
__global__ __launch_bounds__(256, 2) void score_kernel(
    const unsigned char* __restrict__ Yv, const unsigned char* __restrict__ Yt,
    const int* __restrict__ tlen, float* __restrict__ t2v, float* __restrict__ v2t) {
  __shared__ __align__(16) unsigned char As[2][104 * 128];  // 2 x 13312 B
  __shared__ __align__(16) unsigned char Bs[2][80 * 128];   // 2 x 10240 B
  __shared__ float colbuf[4][160];
  __shared__ float rowsum_lds[4][2];

  const int tid = threadIdx.x;
  const int wave = tid >> 6;
  const int lane = tid & 63;
  const int l15 = lane & 15;
  const int quad = lane >> 4;

  // qi-outer / b-inner per-XCD swizzle (keeps the XCD's A working set
  // L2-resident; r3 measured FETCH 285->48 MB).
  const int idx = blockIdx.x;
  const int x = idx & 7;
  const int g = idx >> 3;              // 0..575
  const int qi = g / 12;               // 0..47
  const int bslot = g - qi * 12;       // 0..11
  const int b = bslot * 8 + x;
  const int q0 = qi * 2;

  const unsigned char* Ab = Yv + (long)b * (NV * DE);
  const unsigned char* Bb = Yt + (long)q0 * (NT * DE);

  // ---- zero-init LDS (safety net) ----
  {
    unsigned int* za = (unsigned int*)&As[0][0];
    for (int i = tid; i < 6656; i += 256) za[i] = 0;   // 2*13312 B
    unsigned int* zb = (unsigned int*)&Bs[0][0];
    for (int i = tid; i < 5120; i += 256) zb[i] = 0;   // 2*10240 B
  }
  __syncthreads();

  // ---- staging pointers (bytes) ----
  // segment s covers units s*8..s*8+7; lane: ul=lane>>3, slot=lane&7
  // row = unit*2 + (slot&1); k-quad (16 B) = (slot>>1) ^ (ul&3)
  const int ul = lane >> 3;
  const int slot = lane & 7;
  const int kq16 = (((slot >> 1) ^ (ul & 3)) << 4);  // byte offset in 64-B chunk

  auto a_ptr = [&](int s) -> const unsigned char* {
    int row = (s * 8 + ul) * 2 + (slot & 1);
    if (row > NV - 1) row = NV - 1;
    return Ab + row * DE + kq16;
  };
  auto b_ptr = [&](int s) -> const unsigned char* {
    int r = (s * 8 + ul) * 2 + (slot & 1);
    int half = (r >= 80) ? 1 : 0;
    int t = r - 80 * half;
    if (t > NT - 1) t = NT - 1;
    return Bb + (long)half * (NT * DE) + t * DE + kq16;
  };

  const unsigned char* sp0 = a_ptr(wave);        // A segs 0..3
  const unsigned char* sp1 = a_ptr(wave + 4);    // A segs 4..7
  const unsigned char* sp2 = a_ptr(wave + 8);    // A segs 8..11
  const int s3 = (wave == 1) ? 8 : (wave == 2) ? 9 : 12;
  const int b3_is_b = (wave == 1 || wave == 2);
  const unsigned char* sp3 = b3_is_b ? b_ptr(s3) : a_ptr(12);
  const unsigned char* sp4 = b_ptr(wave);        // B segs 0..3
  const unsigned char* sp5 = b_ptr(wave + 4);    // B segs 4..7
  unsigned char* b3d0 = b3_is_b ? &Bs[0][s3 << 10] : &As[0][12 << 10];
  unsigned char* b3d1 = b3_is_b ? &Bs[1][s3 << 10] : &As[1][12 << 10];

  // ---- k-invariant LDS fragment byte offsets ----
  const int qh = quad >> 1;
  const int q8 = (quad & 1) << 3;
  int aoff[4], boff[10];
  #pragma unroll
  for (int i = 0; i < 4; ++i) {
    int arow = (wave + i * 4) * 16 + l15;
    int u = arow >> 1;
    aoff[i] = (u << 7) + (((qh ^ (u & 3))) << 5) + ((arow & 1) << 4) + q8;
  }
  #pragma unroll
  for (int nt = 0; nt < 10; ++nt) {
    int brow = nt * 16 + l15;
    int u = brow >> 1;
    boff[nt] = (u << 7) + (((qh ^ (u & 3))) << 5) + ((brow & 1) << 4) + q8;
  }

  f32x4 acc[4][10];
  #pragma unroll
  for (int i = 0; i < 4; ++i)
    #pragma unroll
    for (int nt = 0; nt < 10; ++nt)
      acc[i][nt] = (f32x4){0.f, 0.f, 0.f, 0.f};

  auto do_compute = [&](int p) {
    #pragma unroll
    for (int ks = 0; ks < 2; ++ks) {
      const int kx = ks ? 64 : 0;        // flips kq bit 1 in the XOR'd field
      i64 bf[10];
      #pragma unroll
      for (int nt = 0; nt < 10; ++nt)
        bf[nt] = *(const i64*)&Bs[p][boff[nt] ^ kx];
      __builtin_amdgcn_s_setprio(1);
      #pragma unroll
      for (int i = 0; i < 4; ++i) {
        int mt = wave + (i << 2);
        if (mt < 13) {
          i64 af = *(const i64*)&As[p][aoff[i] ^ kx];
          #pragma unroll
          for (int nt = 0; nt < 10; ++nt)
            acc[i][nt] = __builtin_amdgcn_mfma_f32_16x16x32_fp8_fp8(af, bf[nt], acc[i][nt], 0, 0, 0);
        }
      }
      __builtin_amdgcn_s_setprio(0);
    }
  };

  // stage current K-chunk (64 B/row) into buffer p; advance ptrs 64 B
#define SCORE_STAGE(p, b3p)                                              \
  {                                                                      \
    GL16(sp0, &As[p][(wave) << 10], 0);                                  \
    GL16(sp1, &As[p][(wave + 4) << 10], 0);                              \
    GL16(sp2, &As[p][(wave + 8) << 10], 0);                              \
    GL16(sp3, (b3p), 0);                                                 \
    GL16(sp4, &Bs[p][(wave) << 10], 0);                                  \
    GL16(sp5, &Bs[p][(wave + 4) << 10], 0);                              \
    sp0 += 64; sp1 += 64; sp2 += 64; sp3 += 64; sp4 += 64; sp5 += 64;    \
  }

  // iter c: own-wait (chunk c landed) -> barrier (publish; other buf free)
  // -> stage chunk c+1 -> compute chunk c.
#define SCORE_ITER(cur, b3p, do_stage)                                   \
  {                                                                      \
    asm volatile("s_waitcnt vmcnt(0)" ::: "memory");                     \
    __syncthreads();                                                     \
    if (do_stage) SCORE_STAGE(1 - (cur), b3p);                           \
    do_compute(cur);                                                     \
  }

  SCORE_STAGE(0, b3d0)        // chunk 0 -> buf0
  SCORE_ITER(0, b3d1, 1)      // c0: stage c1 -> buf1
  SCORE_ITER(1, b3d0, 1)      // c1: stage c2 -> buf0
  SCORE_ITER(0, b3d1, 1)      // c2
  SCORE_ITER(1, b3d0, 1)      // c3
  SCORE_ITER(0, b3d1, 1)      // c4
  SCORE_ITER(1, b3d0, 1)      // c5
  SCORE_ITER(0, b3d1, 1)      // c6: stage c7 -> buf1
  SCORE_ITER(1, b3d0, 0)      // c7: no stage

#undef SCORE_ITER
#undef SCORE_STAGE

  const int len0 = tlen[q0];
  const int len1 = tlen[q0 + 1];

  // ---- column max over valid v rows (t2v path), both q halves ----
  #pragma unroll
  for (int nt = 0; nt < 10; ++nt) {
    float m = -1e30f;
    #pragma unroll
    for (int i = 0; i < 4; ++i) {
      int mt = wave + (i << 2);
      if (mt < 13) {
        int mbase = mt * 16 + quad * 4;
        #pragma unroll
        for (int r = 0; r < 4; ++r)
          if (mbase + r < NV) m = fmaxf(m, acc[i][nt][r]);
      }
    }
    m = fmaxf(m, __shfl_xor(m, 16));
    m = fmaxf(m, __shfl_xor(m, 32));
    if (lane < 16) colbuf[wave][nt * 16 + l15] = m;
  }

  // ---- row max over valid t cols (v2t path), per q half ----
  float psum[2] = {0.f, 0.f};
  #pragma unroll
  for (int h = 0; h < 2; ++h) {
    int len = h ? len1 : len0;
    #pragma unroll
    for (int i = 0; i < 4; ++i) {
      int mt = wave + (i << 2);
      if (mt < 13) {
        int mbase = mt * 16 + quad * 4;
        #pragma unroll
        for (int r = 0; r < 4; ++r) {
          float rm = -1e30f;
          #pragma unroll
          for (int nt = 0; nt < 5; ++nt) {
            int c = nt * 16 + l15;
            if (c < len) rm = fmaxf(rm, acc[i][h * 5 + nt][r]);
          }
          rm = fmaxf(rm, __shfl_xor(rm, 1));
          rm = fmaxf(rm, __shfl_xor(rm, 2));
          rm = fmaxf(rm, __shfl_xor(rm, 4));
          rm = fmaxf(rm, __shfl_xor(rm, 8));
          if (len < NT) rm = fmaxf(rm, 0.f);  // masked zeros participate in max
          if (l15 == 0 && (mbase + r) < NV) psum[h] += rm;
        }
      }
    }
    psum[h] += __shfl_xor(psum[h], 16);
    psum[h] += __shfl_xor(psum[h], 32);
  }
  if (lane == 0) { rowsum_lds[wave][0] = psum[0]; rowsum_lds[wave][1] = psum[1]; }
  __syncthreads();

  if (wave < 2) {
    int q = q0 + wave;
    int len = wave ? len1 : len0;
    int cbase = wave * 80;
    float ssum = 0.f;
    for (int c = lane; c < 80; c += 64) {
      if (c < len) {
        float m = fmaxf(fmaxf(colbuf[0][cbase + c], colbuf[1][cbase + c]),
                        fmaxf(colbuf[2][cbase + c], colbuf[3][cbase + c]));
        ssum += m;
      }
    }
    ssum += __shfl_xor(ssum, 1);
    ssum += __shfl_xor(ssum, 2);
    ssum += __shfl_xor(ssum, 4);
    ssum += __shfl_xor(ssum, 8);
    ssum += __shfl_xor(ssum, 16);
    ssum += __shfl_xor(ssum, 32);
    if (lane == 0) {
      float rs = rowsum_lds[0][wave] + rowsum_lds[1][wave] +
                 rowsum_lds[2][wave] + rowsum_lds[3][wave];
      t2v[b * NQ + q] = ssum / (float)len;
      v2t[b * NQ + q] = rs / (float)NV;
    }
  }
}

// ---------------------------------------------------------------------------
extern "C" void kernel_launch(void* const* d_in, const int* in_sizes, int n_in,
                              void* d_out, int out_size, void* d_ws, size_t ws_size,
                              hipStream_t stream) {
  (void)in_sizes; (void)n_in; (void)out_size; (void)ws_size;
  const float* visual_cls     = (const float*)d_in[0];
  const float* visual_tokens  = (const float*)d_in[1];
  const float* textual_cls    = (const float*)d_in[2];
  const float* textual_tokens = (const float*)d_in[3];
  const float* Wv_cls = (const float*)d_in[4];
  const float* bv_cls = (const float*)d_in[5];
  const float* Wt_cls = (const float*)d_in[6];
  const float* bt_cls = (const float*)d_in[7];
  const float* Wv_tok = (const float*)d_in[8];
  const float* bv_tok = (const float*)d_in[9];
  const float* Wt_tok = (const float*)d_in[10];
  const float* bt_tok = (const float*)d_in[11];
  const int* text_length = (const int*)d_in[12];

  float* out = (float*)d_out;
  float* v_cls_o = out;
  float* t_cls_o = out + 49152;
  float* t2v_o   = out + 98304;
  float* v2t_o   = out + 107520;

  char* ws = (char*)d_ws;
  unsigned short* Wvb = (unsigned short*)(ws);
  unsigned short* Wtb = (unsigned short*)(ws + 786432);
  unsigned char*  Yv  = (unsigned char*)(ws + 1572864);               // 96*197*512 B
  unsigned char*  Yt  = (unsigned char*)(ws + 1572864 + 9683968);     // 96*77*512 B

  prep_kernel<<<960, 256, 0, stream>>>(
      Wv_tok, Wvb, Wt_tok, Wtb,
      visual_cls, Wv_cls, bv_cls, v_cls_o,
      textual_cls, Wt_cls, bt_cls, t_cls_o);

  proj_norm_kernel<<<412, 256, 0, stream>>>(
      visual_tokens, Wvb, bv_tok, Yv,
      textual_tokens, Wtb, bt_tok, Yt);

  score_kernel<<<(NB * NQ) / 2, 256, 0, stream>>>(Yv, Yt, text_length, t2v_o, v2t_o);
}

// Round 7
// 405.006 us; speedup vs baseline: 2.5063x; 1.0290x over previous
//
#include <hip/hip_runtime.h>

// Problem constants
#define NB 96
#define NQ 96
#define NV 197
#define NT 77
#define DK 768
#define DE 512

typedef __attribute__((ext_vector_type(8))) short s16x8;
typedef __attribute__((ext_vector_type(4))) float f32x4;
typedef long long i64;

__device__ __forceinline__ unsigned short f2bf(float f) {
  union { float f; unsigned int u; } v; v.f = f;
  unsigned int u = v.u;
  unsigned int r = u + 0x7fffu + ((u >> 16) & 1u);
  return (unsigned short)(r >> 16);
}

__device__ __forceinline__ unsigned int pack2bf(float a, float b) {
  return (unsigned int)f2bf(a) | ((unsigned int)f2bf(b) << 16);
}

// f32 -> OCP e4m3fn, round-to-nearest-even.  Inputs here are l2-normalized
// (|x| <= 1) so saturation never triggers; kept for safety.  Never emits
// 0x7F/0xFF (NaN) — clamps to 0x7E.
__device__ __forceinline__ unsigned char f2fp8(float x) {
  union { float f; unsigned u; } v; v.f = x;
  unsigned s = (v.u >> 24) & 0x80;
  v.u &= 0x7FFFFFFFu;
  if (v.f < 0.015625f) {                       // |x| < 2^-6 -> subnormal
    int q = __float2int_rn(v.f * 512.0f);      // RNE; q in 0..8
    return (unsigned char)(s | (unsigned)q);
  }
  if (v.f >= 464.0f) return (unsigned char)(s | 0x7E);  // clamp to 448
  int e8 = (int)((v.u >> 23) & 0xFF) - 120;    // e4m3 biased exponent (bias 7)
  unsigned m = v.u & 0x7FFFFFu;
  unsigned t = ((unsigned)e8 << 3) | (m >> 20);
  unsigned r = m & 0xFFFFFu;
  t += (r > 0x80000u) || ((r == 0x80000u) && (t & 1u));
  if (t > 0x7Eu) t = 0x7Eu;
  return (unsigned char)(s | t);
}

// global -> LDS direct, 16B/lane.  LDS dest = uniform base + lane*16.
#define GL16(gp, lp, off)                                                \
  __builtin_amdgcn_global_load_lds(                                      \
      (const __attribute__((address_space(1))) void*)(gp),               \
      (__attribute__((address_space(3))) void*)(lp), 16, (off), 0)

#define VM_DRAIN() asm volatile("s_waitcnt vmcnt(0) lgkmcnt(0)" ::: "memory")

// ---------------------------------------------------------------------------
// K_prep: fused  cvt(Wv) | cvt(Wt) | cls_v | cls_t   via blockIdx ranges.
// ---------------------------------------------------------------------------
__global__ __launch_bounds__(256) void prep_kernel(
    const float* __restrict__ Wv_tok, unsigned short* __restrict__ Wvb,
    const float* __restrict__ Wt_tok, unsigned short* __restrict__ Wtb,
    const float* __restrict__ visual_cls, const float* __restrict__ Wv_cls,
    const float* __restrict__ bv_cls, float* __restrict__ v_cls_o,
    const float* __restrict__ textual_cls, const float* __restrict__ Wt_cls,
    const float* __restrict__ bt_cls, float* __restrict__ t_cls_o) {
  __shared__ float xs[DK];
  const int blk = blockIdx.x;
  const int tid = threadIdx.x;

  if (blk < 768) {
    const float* src = (blk < 384) ? Wv_tok : Wt_tok;
    unsigned short* dst = (blk < 384) ? Wvb : Wtb;
    int i = ((blk < 384) ? blk : (blk - 384)) * 256 + tid;
    float4 x = ((const float4*)src)[i];
    ushort4 h;
    h.x = f2bf(x.x); h.y = f2bf(x.y); h.z = f2bf(x.z); h.w = f2bf(x.w);
    ((ushort4*)dst)[i] = h;
    return;
  }
  const int is_t = (blk >= 864);
  const int row = blk - (is_t ? 864 : 768);
  const float* X = is_t ? textual_cls : visual_cls;
  const float* W = is_t ? Wt_cls : Wv_cls;
  const float* bias = is_t ? bt_cls : bv_cls;
  float* out = is_t ? t_cls_o : v_cls_o;

  const float* xr = X + (long)row * DK;
  for (int i = tid; i < DK; i += 256) xs[i] = xr[i];
  __syncthreads();
  for (int c = tid; c < DE; c += 256) {
    const float* wr = W + (long)c * DK;
    float s = 0.f;
    #pragma unroll 4
    for (int k = 0; k < DK; k += 4) {
      float4 w4 = *(const float4*)(wr + k);
      s += xs[k] * w4.x + xs[k + 1] * w4.y + xs[k + 2] * w4.z + xs[k + 3] * w4.w;
    }
    out[(long)row * DE + c] = s + bias[c];
  }
}

// ---------------------------------------------------------------------------
// K_proj: fused token projection + bias + l2norm for BOTH modalities.
// Output Y is FP8 e4m3fn (norm computed in f32 first).
// ---------------------------------------------------------------------------
__global__ __launch_bounds__(256, 2) void proj_norm_kernel(
    const float* __restrict__ Xv, const unsigned short* __restrict__ Wvb,
    const float* __restrict__ bv, unsigned char* __restrict__ Yv,
    const float* __restrict__ Xt, const unsigned short* __restrict__ Wtb,
    const float* __restrict__ bt, unsigned char* __restrict__ Yt) {
  __shared__ __align__(16) unsigned short Ws[512 * 64];  // 65536 B
  __shared__ __align__(16) unsigned short Xs[64 * 64];   // 8192 B
  __shared__ float ssq_lds[4][64];

  const int blk = blockIdx.x;
  const int is_t = (blk >= 296);
  const float* X = is_t ? Xt : Xv;
  const unsigned short* Wb = is_t ? Wtb : Wvb;
  const float* bias = is_t ? bt : bv;
  unsigned char* Y = is_t ? Yt : Yv;
  const int M = is_t ? (NQ * NT) : (NB * NV);
  const long row0 = (long)(is_t ? (blk - 296) : blk) * 64;

  const int tid = threadIdx.x;
  const int wave = tid >> 6;
  const int lane = tid & 63;
  const int l15 = lane & 15;
  const int quad = lane >> 4;

  const int sub = lane >> 3;                 // 0..7
  const int swz = ((lane & 7) ^ sub) << 3;   // element offset
  const unsigned short* pw_base = Wb + (long)(wave * 8 + sub) * DK + swz;

  const int xrow_a = tid >> 3;               // 0..31
  const int xrow_b = xrow_a + 32;            // 32..63
  const int xs8 = tid & 7;
  long gra = row0 + xrow_a; if (gra > M - 1) gra = M - 1;
  long grb = row0 + xrow_b; if (grb > M - 1) grb = M - 1;
  const float* px_a = X + gra * DK + xs8 * 8;
  const float* px_b = X + grb * DK + xs8 * 8;
  const int xaddr_a = (xrow_a << 6) + ((xs8 ^ (xrow_a & 7)) << 3);
  const int xaddr_b = (xrow_b << 6) + ((xs8 ^ (xrow_b & 7)) << 3);

  f32x4 acc[4][8];
  #pragma unroll
  for (int m = 0; m < 4; ++m)
    #pragma unroll
    for (int n = 0; n < 8; ++n)
      acc[m][n] = (f32x4){0.f, 0.f, 0.f, 0.f};

  for (int kc = 0; kc < DK; kc += 64) {
    __syncthreads();
    {
      float4 x0 = *(const float4*)(px_a);
      float4 x1 = *(const float4*)(px_a + 4);
      uint4 h;
      h.x = pack2bf(x0.x, x0.y); h.y = pack2bf(x0.z, x0.w);
      h.z = pack2bf(x1.x, x1.y); h.w = pack2bf(x1.z, x1.w);
      *(uint4*)(&Xs[xaddr_a]) = h;
      x0 = *(const float4*)(px_b);
      x1 = *(const float4*)(px_b + 4);
      h.x = pack2bf(x0.x, x0.y); h.y = pack2bf(x0.z, x0.w);
      h.z = pack2bf(x1.x, x1.y); h.w = pack2bf(x1.z, x1.w);
      *(uint4*)(&Xs[xaddr_b]) = h;
      px_a += 64; px_b += 64;
    }
    {
      const unsigned short* pw = pw_base;
      #pragma unroll
      for (int j = 0; j < 16; ++j) {
        GL16(pw, &Ws[(j * 4 + wave) << 9], 0);
        pw += 32 * DK;
      }
      pw_base += 64;
    }
    VM_DRAIN();
    __syncthreads();
    #pragma unroll
    for (int ks = 0; ks < 2; ++ks) {
      s16x8 af[4];
      #pragma unroll
      for (int mi = 0; mi < 4; ++mi) {
        int arow = mi * 16 + l15;
        af[mi] = *(const s16x8*)&Xs[(arow << 6) + ((((ks << 2) + quad) ^ (arow & 7)) << 3)];
      }
      #pragma unroll
      for (int nt = 0; nt < 8; ++nt) {
        int wrow = wave * 128 + nt * 16 + l15;
        s16x8 bfr = *(const s16x8*)&Ws[(wrow << 6) + ((((ks << 2) + quad) ^ (wrow & 7)) << 3)];
        #pragma unroll
        for (int mi = 0; mi < 4; ++mi)
          acc[mi][nt] = __builtin_amdgcn_mfma_f32_16x16x32_bf16(af[mi], bfr, acc[mi][nt], 0, 0, 0);
      }
    }
  }

  #pragma unroll
  for (int nt = 0; nt < 8; ++nt) {
    float bc = bias[wave * 128 + nt * 16 + l15];
    #pragma unroll
    for (int mi = 0; mi < 4; ++mi) {
      acc[mi][nt].x += bc; acc[mi][nt].y += bc; acc[mi][nt].z += bc; acc[mi][nt].w += bc;
    }
  }

  #pragma unroll
  for (int mi = 0; mi < 4; ++mi)
    #pragma unroll
    for (int r = 0; r < 4; ++r) {
      float t = 0.f;
      #pragma unroll
      for (int nt = 0; nt < 8; ++nt) { float v = acc[mi][nt][r]; t += v * v; }
      t += __shfl_xor(t, 1);
      t += __shfl_xor(t, 2);
      t += __shfl_xor(t, 4);
      t += __shfl_xor(t, 8);
      if (l15 == 0) ssq_lds[wave][mi * 16 + quad * 4 + r] = t;
    }
  __syncthreads();

  #pragma unroll
  for (int mi = 0; mi < 4; ++mi) {
    #pragma unroll
    for (int r = 0; r < 4; ++r) {
      int rr = mi * 16 + quad * 4 + r;
      float tot = ssq_lds[0][rr] + ssq_lds[1][rr] + ssq_lds[2][rr] + ssq_lds[3][rr];
      float scale = (tot > 0.f) ? (1.f / fmaxf(sqrtf(tot), 1e-12f)) : 0.f;
      long grow = row0 + rr;
      if (grow < M) {
        #pragma unroll
        for (int nt = 0; nt < 8; ++nt) {
          int col = wave * 128 + nt * 16 + l15;
          Y[grow * DE + col] = f2fp8(acc[mi][nt][r] * scale);
        }
      }
    }
  }
}

// ---------------------------------------------------------------------------
// K3: fused similarity + masked max/sum reductions.  FP8 e4m3 inputs.
// r6 post-mortem: occupancy is AGPR-capped at 2 blocks/CU (acc = 160 AGPRs,
// class 129-256 -> 8 waves/CU); depth-1 vs depth-2 pipelining identical ->
// the cost was the 8x/block barrier-lockstep rhythm, not load latency.
// NEW STRUCTURE: zero barriers in the k-loop.
//  - A: direct global->VGPR fragment loads (A has no cross-wave reuse;
//    LDS staging was a pure pass-through).  Depth-1 register prefetch,
//    static af0/af1 rotation.  addr = row*512 + c*64 + ks*32 + quad*8
//    (same algebra as the verified LDS fragment path).
//  - B: staged ONCE for all 8 K-chunks (4x cross-wave reuse), packed at
//    77 rows per q-half: [chunk c][unit u<77][slot] = c*9856 + u*128,
//    same XOR-kq involution (u&3).  One stage + ONE barrier total.
//    Segment 9 of each chunk covers units 69..76 (overlap rewrite of
//    69..71 with identical data — benign).  384-B zeroed slack absorbs
//    the masked u=77..79 reads of chunk 7.
//  - colbuf/rowsum alias into the B pool after a post-k-loop barrier.
//    LDS = 79232 B/block -> 2 blocks/CU preserved.
//  - Epilogue q-half boundary is now 77 (col = 77*h + t).
// ---------------------------------------------------------------------------
__global__ __launch_bounds__(256, 2) void score_kernel(
    const unsigned char* __restrict__ Yv, const unsigned char* __restrict__ Yt,
    const int* __restrict__ tlen, float* __restrict__ t2v, float* __restrict__ v2t) {
  __shared__ __align__(16) unsigned char pool[79232];  // B panel + slack
  float (*colbuf)[160] = (float(*)[160])pool;          // aliased after k-loop
  float (*rowsum_lds)[2] = (float(*)[2])(pool + 2560);

  const int tid = threadIdx.x;
  const int wave = tid >> 6;
  const int lane = tid & 63;
  const int l15 = lane & 15;
  const int quad = lane >> 4;

  // qi-outer / b-inner per-XCD swizzle (keeps the XCD's A working set
  // L2-resident; r3 measured FETCH 285->48 MB).
  const int idx = blockIdx.x;
  const int x = idx & 7;
  const int g = idx >> 3;              // 0..575
  const int qi = g / 12;               // 0..47
  const int bslot = g - qi * 12;       // 0..11
  const int b = bslot * 8 + x;
  const int q0 = qi * 2;

  const unsigned char* Ab = Yv + (long)b * (NV * DE);
  const unsigned char* Bb = Yt + (long)q0 * (NT * DE);

  // ---- zero the 384-B slack (absorbs masked u=77..79 reads of chunk 7) ----
  if (tid < 96) *(int*)(pool + 78848 + tid * 4) = 0;

  // ---- A fragment pointers (k-invariant), rows clamped to 196 ----
  const unsigned char* pa[4];
  #pragma unroll
  for (int i = 0; i < 4; ++i) {
    int row = (wave + (i << 2)) * 16 + l15;
    if (row > NV - 1) row = NV - 1;
    pa[i] = Ab + row * DE + (quad << 3);
  }

  // ---- stage FULL B panel: wave w stages chunks 2w, 2w+1 (10 segs each) ----
  const int ul = lane >> 3;
  const int slot = lane & 7;
  #pragma unroll
  for (int cc = 0; cc < 2; ++cc) {
    const int c = wave * 2 + cc;
    const unsigned char* cb = Bb + c * 64;
    #pragma unroll
    for (int s = 0; s < 10; ++s) {
      int u = (s < 9) ? (s * 8 + ul) : (69 + ul);
      int r = u * 2 + (slot & 1);          // 0..153
      int h = (r >= NT);
      int t = r - NT * h;
      const unsigned char* gp = cb + ((long)h * NT + t) * DE + (((slot >> 1) ^ (u & 3)) << 4);
      int sbase = (s < 9) ? (s << 10) : 8832;
      GL16(gp, pool + c * 9856 + sbase, 0);
    }
  }

  // ---- k-invariant B fragment byte offsets (within a chunk region) ----
  const int qh = quad >> 1;
  const int q8 = (quad & 1) << 3;
  int boff[10];
  #pragma unroll
  for (int nt = 0; nt < 10; ++nt) {
    int brow = nt * 16 + l15;
    int u = brow >> 1;
    boff[nt] = (u << 7) + ((qh ^ (u & 3)) << 5) + ((brow & 1) << 4) + q8;
  }

  f32x4 acc[4][10];
  #pragma unroll
  for (int i = 0; i < 4; ++i)
    #pragma unroll
    for (int nt = 0; nt < 10; ++nt)
      acc[i][nt] = (f32x4){0.f, 0.f, 0.f, 0.f};

  auto do_compute = [&](int c, const i64* af) {
    const int base = c * 9856;
    #pragma unroll
    for (int ks = 0; ks < 2; ++ks) {
      const int kx = ks ? 64 : 0;
      i64 bf[10];
      #pragma unroll
      for (int nt = 0; nt < 10; ++nt)
        bf[nt] = *(const i64*)&pool[base + (boff[nt] ^ kx)];
      __builtin_amdgcn_s_setprio(1);
      #pragma unroll
      for (int i = 0; i < 4; ++i) {
        if (wave + (i << 2) < 13) {
          #pragma unroll
          for (int nt = 0; nt < 10; ++nt)
            acc[i][nt] = __builtin_amdgcn_mfma_f32_16x16x32_fp8_fp8(
                af[i * 2 + ks], bf[nt], acc[i][nt], 0, 0, 0);
        }
      }
      __builtin_amdgcn_s_setprio(0);
    }
  };

#define LOADA(c, af)                                                     \
  {                                                                      \
    _Pragma("unroll")                                                    \
    for (int i = 0; i < 4; ++i) {                                        \
      if (wave + (i << 2) < 13) {                                        \
        af[i * 2]     = *(const i64*)(pa[i] + (c) * 64);                 \
        af[i * 2 + 1] = *(const i64*)(pa[i] + (c) * 64 + 32);            \
      }                                                                  \
    }                                                                    \
  }

  i64 af0[8] = {0, 0, 0, 0, 0, 0, 0, 0};
  i64 af1[8] = {0, 0, 0, 0, 0, 0, 0, 0};

  LOADA(0, af0)
  VM_DRAIN();          // B stage + first A fragments all landed
  __syncthreads();     // the ONLY barrier before the k-loop

  LOADA(1, af1)  do_compute(0, af0);
  LOADA(2, af0)  do_compute(1, af1);
  LOADA(3, af1)  do_compute(2, af0);
  LOADA(4, af0)  do_compute(3, af1);
  LOADA(5, af1)  do_compute(4, af0);
  LOADA(6, af0)  do_compute(5, af1);
  LOADA(7, af1)  do_compute(6, af0);
  do_compute(7, af1);

#undef LOADA

  __syncthreads();     // B pool dead -> colbuf aliasing safe

  const int len0 = tlen[q0];
  const int len1 = tlen[q0 + 1];

  // ---- column max over valid v rows (t2v path), global cols 0..159 ----
  #pragma unroll
  for (int nt = 0; nt < 10; ++nt) {
    float m = -1e30f;
    #pragma unroll
    for (int i = 0; i < 4; ++i) {
      int mt = wave + (i << 2);
      if (mt < 13) {
        int mbase = mt * 16 + quad * 4;
        #pragma unroll
        for (int r = 0; r < 4; ++r)
          if (mbase + r < NV) m = fmaxf(m, acc[i][nt][r]);
      }
    }
    m = fmaxf(m, __shfl_xor(m, 16));
    m = fmaxf(m, __shfl_xor(m, 32));
    if (lane < 16) colbuf[wave][nt * 16 + l15] = m;
  }

  // ---- row max over valid t cols (v2t path); q-half boundary at 77 ----
  float psum[2] = {0.f, 0.f};
  #pragma unroll
  for (int i = 0; i < 4; ++i) {
    int mt = wave + (i << 2);
    if (mt < 13) {
      int mbase = mt * 16 + quad * 4;
      #pragma unroll
      for (int r = 0; r < 4; ++r) {
        // half 0: cols 0..len0-1 (nt 0..4)
        float rm = -1e30f;
        #pragma unroll
        for (int nt = 0; nt < 5; ++nt) {
          int gcol = nt * 16 + l15;
          if (gcol < len0) rm = fmaxf(rm, acc[i][nt][r]);
        }
        rm = fmaxf(rm, __shfl_xor(rm, 1));
        rm = fmaxf(rm, __shfl_xor(rm, 2));
        rm = fmaxf(rm, __shfl_xor(rm, 4));
        rm = fmaxf(rm, __shfl_xor(rm, 8));
        if (len0 < NT) rm = fmaxf(rm, 0.f);  // masked zeros participate
        if (l15 == 0 && (mbase + r) < NV) psum[0] += rm;
        // half 1: cols 77..77+len1-1 (nt 4..9)
        float rm1 = -1e30f;
        #pragma unroll
        for (int nt = 4; nt < 10; ++nt) {
          int gcol = nt * 16 + l15;
          if (gcol >= NT && gcol < NT + len1) rm1 = fmaxf(rm1, acc[i][nt][r]);
        }
        rm1 = fmaxf(rm1, __shfl_xor(rm1, 1));
        rm1 = fmaxf(rm1, __shfl_xor(rm1, 2));
        rm1 = fmaxf(rm1, __shfl_xor(rm1, 4));
        rm1 = fmaxf(rm1, __shfl_xor(rm1, 8));
        if (len1 < NT) rm1 = fmaxf(rm1, 0.f);
        if (l15 == 0 && (mbase + r) < NV) psum[1] += rm1;
      }
    }
  }
  psum[0] += __shfl_xor(psum[0], 16);
  psum[0] += __shfl_xor(psum[0], 32);
  psum[1] += __shfl_xor(psum[1], 16);
  psum[1] += __shfl_xor(psum[1], 32);
  if (lane == 0) { rowsum_lds[wave][0] = psum[0]; rowsum_lds[wave][1] = psum[1]; }
  __syncthreads();

  if (wave < 2) {
    int q = q0 + wave;
    int len = wave ? len1 : len0;
    int cbase = wave * NT;   // q-half boundary at 77
    float ssum = 0.f;
    for (int c = lane; c < NT; c += 64) {
      if (c < len) {
        float m = fmaxf(fmaxf(colbuf[0][cbase + c], colbuf[1][cbase + c]),
                        fmaxf(colbuf[2][cbase + c], colbuf[3][cbase + c]));
        ssum += m;
      }
    }
    ssum += __shfl_xor(ssum, 1);
    ssum += __shfl_xor(ssum, 2);
    ssum += __shfl_xor(ssum, 4);
    ssum += __shfl_xor(ssum, 8);
    ssum += __shfl_xor(ssum, 16);
    ssum += __shfl_xor(ssum, 32);
    if (lane == 0) {
      float rs = rowsum_lds[0][wave] + rowsum_lds[1][wave] +
                 rowsum_lds[2][wave] + rowsum_lds[3][wave];
      t2v[b * NQ + q] = ssum / (float)len;
      v2t[b * NQ + q] = rs / (float)NV;
    }
  }
}

// ---------------------------------------------------------------------------
extern "C" void kernel_launch(void* const* d_in, const int* in_sizes, int n_in,
                              void* d_out, int out_size, void* d_ws, size_t ws_size,
                              hipStream_t stream) {
  (void)in_sizes; (void)n_in; (void)out_size; (void)ws_size;
  const float* visual_cls     = (const float*)d_in[0];
  const float* visual_tokens  = (const float*)d_in[1];
  const float* textual_cls    = (const float*)d_in[2];
  const float* textual_tokens = (const float*)d_in[3];
  const float* Wv_cls = (const float*)d_in[4];
  const float* bv_cls = (const float*)d_in[5];
  const float* Wt_cls = (const float*)d_in[6];
  const float* bt_cls = (const float*)d_in[7];
  const float* Wv_tok = (const float*)d_in[8];
  const float* bv_tok = (const float*)d_in[9];
  const float* Wt_tok = (const float*)d_in[10];
  const float* bt_tok = (const float*)d_in[11];
  const int* text_length = (const int*)d_in[12];

  float* out = (float*)d_out;
  float* v_cls_o = out;
  float* t_cls_o = out + 49152;
  float* t2v_o   = out + 98304;
  float* v2t_o   = out + 107520;

  char* ws = (char*)d_ws;
  unsigned short* Wvb = (unsigned short*)(ws);
  unsigned short* Wtb = (unsigned short*)(ws + 786432);
  unsigned char*  Yv  = (unsigned char*)(ws + 1572864);               // 96*197*512 B
  unsigned char*  Yt  = (unsigned char*)(ws + 1572864 + 9683968);     // 96*77*512 B

  prep_kernel<<<960, 256, 0, stream>>>(
      Wv_tok, Wvb, Wt_tok, Wtb,
      visual_cls, Wv_cls, bv_cls, v_cls_o,
      textual_cls, Wt_cls, bt_cls, t_cls_o);

  proj_norm_kernel<<<412, 256, 0, stream>>>(
      visual_tokens, Wvb, bv_tok, Yv,
      textual_tokens, Wtb, bt_tok, Yt);

  score_kernel<<<(NB * NQ) / 2, 256, 0, stream>>>(Yv, Yt, text_length, t2v_o, v2t_o);
}